// Round 4
// baseline (130.835 us; speedup 1.0000x reference)
//
#include <hip/hip_runtime.h>
#include <hip/hip_bf16.h>

#define B_ 8
#define C_ 256
#define L_ 1024
#define NH_ 8
#define EPS_ 1e-5f

typedef __attribute__((ext_vector_type(8))) short bf16x8;
typedef __attribute__((ext_vector_type(4))) float f32x4;

static __device__ inline ushort f2bf(float f) {
  union { __hip_bfloat16 b; ushort u; } c;
  c.b = __float2bfloat16(f);
  return c.u;
}

// ---------------------------------------------------------------------------
// Kernel W: convert qkv_w [768,256] and out_w [256,256] fp32 -> bf16
// ---------------------------------------------------------------------------
__global__ __launch_bounds__(256) void wconv_kernel(
    const float4* __restrict__ qw, const float4* __restrict__ ow,
    uint2* __restrict__ wq, uint2* __restrict__ wo) {
  int id = blockIdx.x * 256 + threadIdx.x;
  float4 v;
  uint2* dst;
  if (id < 49152) { v = qw[id]; dst = wq + id; }
  else { v = ow[id - 49152]; dst = wo + (id - 49152); }
  union { ushort s[4]; uint2 u; } p;
  p.s[0] = f2bf(v.x); p.s[1] = f2bf(v.y); p.s[2] = f2bf(v.z); p.s[3] = f2bf(v.w);
  *dst = p.u;
}

// ---------------------------------------------------------------------------
// Kernel A: GroupNorm + depthwise conv k=3, output TRANSPOSED bf16 ht[B][L][256]
// ---------------------------------------------------------------------------
__global__ __launch_bounds__(256) void gn_dwconv_kernel(
    const float* __restrict__ x, const float* __restrict__ gamma,
    const float* __restrict__ beta, const float* __restrict__ dw,
    ushort* __restrict__ ht) {
  int blk = blockIdx.x;           // b*32 + g
  int b = blk >> 5, g = blk & 31;
  int t = threadIdx.x;
  __shared__ float hn[8 * L_];
  __shared__ float ws0[4], ws1[4];
  const size_t base = ((size_t)(b * C_ + g * 8)) * L_;

  float s = 0.f, ss = 0.f;
  float vals[32];
#pragma unroll
  for (int i = 0; i < 32; ++i) {
    int e = t + 256 * i;
    float v = x[base + e];
    vals[i] = v;
    s += v; ss += v * v;
  }
#pragma unroll
  for (int off = 32; off >= 1; off >>= 1) {
    s  += __shfl_xor(s, off);
    ss += __shfl_xor(ss, off);
  }
  int wave = t >> 6;
  if ((t & 63) == 0) { ws0[wave] = s; ws1[wave] = ss; }
  __syncthreads();
  s  = ws0[0] + ws0[1] + ws0[2] + ws0[3];
  ss = ws1[0] + ws1[1] + ws1[2] + ws1[3];
  float mean = s * (1.f / 8192.f);
  float var = ss * (1.f / 8192.f) - mean * mean;
  float rstd = rsqrtf(var + EPS_);

#pragma unroll
  for (int i = 0; i < 32; ++i) {
    int e = t + 256 * i;
    int c = g * 8 + (e >> 10);
    float sc = gamma[c] * rstd;
    hn[e] = (vals[i] - mean) * sc + beta[c];
  }
  __syncthreads();
  float r[32];
#pragma unroll
  for (int i = 0; i < 32; ++i) {
    int e = t + 256 * i;
    int l = e & 1023;
    int c = g * 8 + (i >> 2);
    float w0 = dw[c * 3 + 0], w1 = dw[c * 3 + 1], w2 = dw[c * 3 + 2];
    float a = (l > 0) ? hn[e - 1] : 0.f;
    float m = hn[e];
    float z = (l < 1023) ? hn[e + 1] : 0.f;
    r[i] = w0 * a + w1 * m + w2 * z;
  }
#pragma unroll
  for (int li = 0; li < 4; ++li) {
    int l = t + 256 * li;
    union { ushort s8[8]; uint4 u; } pk;
#pragma unroll
    for (int cl = 0; cl < 8; ++cl) pk.s8[cl] = f2bf(r[4 * cl + li]);
    *(uint4*)(ht + ((size_t)(b * L_ + l)) * 256 + g * 8) = pk.u;
  }
}

// ---------------------------------------------------------------------------
// Kernel B/D: pointwise conv via MFMA. M=l, N=oc, K=c(256).
// ---------------------------------------------------------------------------
template <bool RESID, bool BF16OUT, int OCT>
__global__ __launch_bounds__(256) void pconv_mfma_kernel(
    const ushort* __restrict__ Xt, const ushort* __restrict__ Wb,
    const float* __restrict__ bias, const float* __restrict__ resid,
    void* __restrict__ outv, int OC) {
  constexpr int NN = OCT / 16;
  int b = blockIdx.z;
  int t = threadIdx.x;
  int w = t >> 6, l = t & 63;
  int g = l >> 4, ln = l & 15;
  int wl = w >> 1, wo = w & 1;
  int lbase = blockIdx.x * 128 + wl * 64;
  int ocbase = blockIdx.y * (2 * OCT) + wo * OCT;

  const ushort* xp = Xt + ((size_t)b * L_ + lbase) * 256;
  const ushort* wp = Wb + (size_t)ocbase * 256;

  f32x4 acc[4][NN];
#pragma unroll
  for (int ml = 0; ml < 4; ++ml)
#pragma unroll
    for (int nn = 0; nn < NN; ++nn) acc[ml][nn] = (f32x4){0.f, 0.f, 0.f, 0.f};

  for (int c0 = 0; c0 < 256; c0 += 32) {
    bf16x8 af[4], bf[NN];
#pragma unroll
    for (int ml = 0; ml < 4; ++ml)
      af[ml] = *(const bf16x8*)(xp + (size_t)(16 * ml + ln) * 256 + c0 + 8 * g);
#pragma unroll
    for (int nn = 0; nn < NN; ++nn)
      bf[nn] = *(const bf16x8*)(wp + (size_t)(16 * nn + ln) * 256 + c0 + 8 * g);
#pragma unroll
    for (int ml = 0; ml < 4; ++ml)
#pragma unroll
      for (int nn = 0; nn < NN; ++nn)
        acc[ml][nn] = __builtin_amdgcn_mfma_f32_16x16x32_bf16(af[ml], bf[nn], acc[ml][nn], 0, 0, 0);
  }

#pragma unroll
  for (int nn = 0; nn < NN; ++nn) {
    int oc = ocbase + 16 * nn + ln;
    float bs = bias[oc];
#pragma unroll
    for (int ml = 0; ml < 4; ++ml) {
      int lr = lbase + 16 * ml + 4 * g;
      size_t ob = ((size_t)b * OC + oc) * L_ + lr;
      float rv[4];
#pragma unroll
      for (int r4 = 0; r4 < 4; ++r4) rv[r4] = acc[ml][nn][r4] + bs;
      if (RESID) {
        float4 rd = *(const float4*)(resid + ob);
        rv[0] += rd.x; rv[1] += rd.y; rv[2] += rd.z; rv[3] += rd.w;
      }
      if (BF16OUT) {
        union { ushort s[4]; uint2 u; } pk;
#pragma unroll
        for (int r4 = 0; r4 < 4; ++r4) pk.s[r4] = f2bf(rv[r4]);
        *(uint2*)((ushort*)outv + ob) = pk.u;
      } else {
        float4 st = make_float4(rv[0], rv[1], rv[2], rv[3]);
        *(float4*)((float*)outv + ob) = st;
      }
    }
  }
}

// ---------------------------------------------------------------------------
// Repack: qkvb [B,768,L] bf16 -> qt,kt [bh][L][32] (transposed), vb [bh][32][L]
// ---------------------------------------------------------------------------
__global__ __launch_bounds__(256) void repack_kernel(
    const ushort* __restrict__ qkvb, ushort* __restrict__ qt,
    ushort* __restrict__ kt, ushort* __restrict__ vb) {
  int l0 = blockIdx.x * 256;
  int kind = blockIdx.y;
  int bh = blockIdx.z;
  int b = bh >> 3, hh = bh & 7;
  int t = threadIdx.x;
  const ushort* src = qkvb + ((size_t)(b * 768 + hh * 96 + kind * 32)) * L_;
  int colu = t & 127, rhalf = t >> 7;

  if (kind == 2) {
    const uint* su = (const uint*)src;
    uint* du = (uint*)(vb + (size_t)bh * 32 * L_);
#pragma unroll
    for (int it = 0; it < 16; ++it) {
      int d = it * 2 + rhalf;
      int idx = d * 512 + l0 / 2 + colu;
      du[idx] = su[idx];
    }
  } else {
    __shared__ ushort tile[32][264];
    const uint* su = (const uint*)src;
#pragma unroll
    for (int it = 0; it < 16; ++it) {
      int d = it * 2 + rhalf;
      uint v = su[d * 512 + l0 / 2 + colu];
      tile[d][2 * colu] = (ushort)(v & 0xffff);
      tile[d][2 * colu + 1] = (ushort)(v >> 16);
    }
    __syncthreads();
    ushort* dst = (kind ? kt : qt) + (size_t)bh * L_ * 32;
    uint outv[16];
#pragma unroll
    for (int d2 = 0; d2 < 16; ++d2)
      outv[d2] = (uint)tile[2 * d2][t] | ((uint)tile[2 * d2 + 1][t] << 16);
    uint4* dp = (uint4*)(dst + (size_t)(l0 + t) * 32);
    dp[0] = make_uint4(outv[0], outv[1], outv[2], outv[3]);
    dp[1] = make_uint4(outv[4], outv[5], outv[6], outv[7]);
    dp[2] = make_uint4(outv[8], outv[9], outv[10], outv[11]);
    dp[3] = make_uint4(outv[12], outv[13], outv[14], outv[15]);
  }
}

// ---------------------------------------------------------------------------
// Kernel C: MFMA flash attention, 16 q/wave, KV tile 128, MFMA-summed denom,
// defer-max, XCD swizzle. grid: 1024 blocks x 256 thr. Output ot[B][L][256].
// ---------------------------------------------------------------------------
__global__ __launch_bounds__(256) void attn_mfma_kernel(
    const ushort* __restrict__ qt, const ushort* __restrict__ kt,
    const ushort* __restrict__ vb, ushort* __restrict__ ot) {
  const int id = blockIdx.x;
  // bijective swizzle: all 16 q-tiles of a bh share id&7 -> same XCD
  const int bh = ((id & 7) << 3) | (id >> 7);
  const int qtile = (id >> 3) & 15;
  const int b = bh >> 3, hh = bh & 7;
  const int t = threadIdx.x;
  const int w = t >> 6, l = t & 63;
  const int g = l >> 4, ln = l & 15;
  const int q0b = qtile * 64;
  const int q0 = q0b + w * 16;

  const ushort* qbase = qt + (size_t)bh * (L_ * 32);
  const ushort* kbase = kt + (size_t)bh * (L_ * 32);
  const ushort* vbase = vb + (size_t)bh * (32 * L_);

  const f32x4 z4 = {0.f, 0.f, 0.f, 0.f};
  const bf16x8 bq = *(const bf16x8*)(qbase + (size_t)(q0 + ln) * 32 + g * 8);

  union { ushort s[8]; bf16x8 v; } onesu;
#pragma unroll
  for (int i = 0; i < 8; ++i) onesu.s[i] = 0x3F80;  // bf16 1.0
  const bf16x8 ones = onesu.v;

  f32x4 oacc0 = z4, oacc1 = z4, oaccS = z4;
  float M = -3e38f;
  const float cs = 0.0625f * 1.44269504f;  // scale * log2(e)

  const ushort* kp0 = kbase + ln * 32 + g * 8;
  const ushort* vp0 = vbase + (size_t)ln * L_ + 4 * g;

#pragma unroll 2
  for (int kv0 = 0; kv0 < L_; kv0 += 128) {
    // QK^T: S^T[kv][q], 8 x MFMA
    f32x4 sacc[8];
#pragma unroll
    for (int mk = 0; mk < 8; ++mk) {
      bf16x8 ak = *(const bf16x8*)(kp0 + (size_t)(kv0 + 16 * mk) * 32);
      sacc[mk] = __builtin_amdgcn_mfma_f32_16x16x32_bf16(ak, bq, z4, 0, 0, 0);
    }

    // tile max, explicit tree (v_max3-friendly)
    float mx[8];
#pragma unroll
    for (int mk = 0; mk < 8; ++mk)
      mx[mk] = fmaxf(fmaxf(sacc[mk][0], sacc[mk][1]), fmaxf(sacc[mk][2], sacc[mk][3]));
    float a0 = fmaxf(mx[0], mx[1]), a1 = fmaxf(mx[2], mx[3]);
    float a2 = fmaxf(mx[4], mx[5]), a3 = fmaxf(mx[6], mx[7]);
    float mt = fmaxf(fmaxf(a0, a1), fmaxf(a2, a3));
    mt = fmaxf(mt, __shfl_xor(mt, 16));
    mt = fmaxf(mt, __shfl_xor(mt, 32));

    // defer-max: only rescale when tile max grew past threshold (log2 units)
    if (!__all((mt - M) * cs <= 8.f)) {
      float Mn = fmaxf(M, mt);
      float corr = exp2f((M - Mn) * cs);
#pragma unroll
      for (int r = 0; r < 4; ++r) {
        oacc0[r] *= corr; oacc1[r] *= corr; oaccS[r] *= corr;
      }
      M = Mn;
    }
    float em = M * cs;

    // exp in place + pack to bf16
    uint upk[8][2];
#pragma unroll
    for (int mk = 0; mk < 8; ++mk) {
#pragma unroll
      for (int r = 0; r < 4; ++r) sacc[mk][r] = exp2f(sacc[mk][r] * cs - em);
      uint u0, u1;
      asm("v_cvt_pk_bf16_f32 %0, %1, %2" : "=v"(u0) : "v"(sacc[mk][0]), "v"(sacc[mk][1]));
      asm("v_cvt_pk_bf16_f32 %0, %1, %2" : "=v"(u1) : "v"(sacc[mk][2]), "v"(sacc[mk][3]));
      upk[mk][0] = u0; upk[mk][1] = u1;
    }

    // PV + denominator via MFMA (A = ones)
    __builtin_amdgcn_s_setprio(1);
#pragma unroll
    for (int ks = 0; ks < 4; ++ks) {
      union { uint u[4]; bf16x8 v; } pb;
      pb.u[0] = upk[2 * ks][0];
      pb.u[1] = upk[2 * ks][1];
      pb.u[2] = upk[2 * ks + 1][0];
      pb.u[3] = upk[2 * ks + 1][1];
      oaccS = __builtin_amdgcn_mfma_f32_16x16x32_bf16(ones, pb.v, oaccS, 0, 0, 0);
      const ushort* vrb = vp0 + kv0 + 32 * ks;
      uint2 lo0 = *(const uint2*)(vrb);
      uint2 hi0 = *(const uint2*)(vrb + 16);
      uint2 lo1 = *(const uint2*)(vrb + 16 * L_);
      uint2 hi1 = *(const uint2*)(vrb + 16 * L_ + 16);
      union { uint u[4]; bf16x8 v; } av0, av1;
      av0.u[0] = lo0.x; av0.u[1] = lo0.y; av0.u[2] = hi0.x; av0.u[3] = hi0.y;
      av1.u[0] = lo1.x; av1.u[1] = lo1.y; av1.u[2] = hi1.x; av1.u[3] = hi1.y;
      oacc0 = __builtin_amdgcn_mfma_f32_16x16x32_bf16(av0.v, pb.v, oacc0, 0, 0, 0);
      oacc1 = __builtin_amdgcn_mfma_f32_16x16x32_bf16(av1.v, pb.v, oacc1, 0, 0, 0);
    }
    __builtin_amdgcn_s_setprio(0);
  }

  // epilogue: normalize, LDS transpose, write ot[B][L][256]
  __shared__ __align__(16) ushort tile[64][40];
  float rl = 1.f / oaccS[0];
  int q_loc = w * 16 + ln;
  ushort4 pk0, pk1;
  pk0.x = f2bf(oacc0[0] * rl); pk0.y = f2bf(oacc0[1] * rl);
  pk0.z = f2bf(oacc0[2] * rl); pk0.w = f2bf(oacc0[3] * rl);
  pk1.x = f2bf(oacc1[0] * rl); pk1.y = f2bf(oacc1[1] * rl);
  pk1.z = f2bf(oacc1[2] * rl); pk1.w = f2bf(oacc1[3] * rl);
  *(ushort4*)&tile[q_loc][4 * g] = pk0;
  *(ushort4*)&tile[q_loc][16 + 4 * g] = pk1;
  __syncthreads();
  {
    int row = t >> 2, ch = t & 3;
    uint2 v0 = *(const uint2*)&tile[row][ch * 8];
    uint2 v1 = *(const uint2*)&tile[row][ch * 8 + 4];
    uint4 v = make_uint4(v0.x, v0.y, v1.x, v1.y);
    *(uint4*)(ot + ((size_t)(b * L_ + q0b + row)) * 256 + hh * 32 + ch * 8) = v;
  }
}

// ---------------------------------------------------------------------------
extern "C" void kernel_launch(void* const* d_in, const int* in_sizes, int n_in,
                              void* d_out, int out_size, void* d_ws, size_t ws_size,
                              hipStream_t stream) {
  const float* x      = (const float*)d_in[0];
  const float* gamma  = (const float*)d_in[1];
  const float* beta   = (const float*)d_in[2];
  const float* dw     = (const float*)d_in[3];
  const float* qkv_w  = (const float*)d_in[4];
  const float* qkv_b  = (const float*)d_in[5];
  const float* out_w  = (const float*)d_in[6];
  const float* out_b  = (const float*)d_in[7];
  float* out = (float*)d_out;

  char* ws = (char*)d_ws;
  ushort* ht   = (ushort*)(ws);                   // 4 MiB @0  (dead after qkv)
  ushort* qkvb = (ushort*)(ws + (4u << 20));      // 12 MiB @4 (dead after repack)
  ushort* qtb  = (ushort*)(ws + (16u << 20));     // 4 MiB @16
  ushort* ktb  = (ushort*)(ws + (20u << 20));     // 4 MiB @20
  ushort* vbb  = (ushort*)(ws + (24u << 20));     // 4 MiB @24
  ushort* otb  = (ushort*)(ws);                   // 4 MiB @0  (reuse ht)
  ushort* wq   = (ushort*)(ws + (28u << 20));     // 384 KiB @28M
  ushort* wo   = (ushort*)(ws + (28u << 20) + (512u << 10));  // 128 KiB

  wconv_kernel<<<256, 256, 0, stream>>>((const float4*)qkv_w, (const float4*)out_w,
                                        (uint2*)wq, (uint2*)wo);
  gn_dwconv_kernel<<<B_ * 32, 256, 0, stream>>>(x, gamma, beta, dw, ht);
  pconv_mfma_kernel<false, true, 64><<<dim3(8, 6, B_), 256, 0, stream>>>(
      ht, wq, qkv_b, nullptr, (void*)qkvb, 768);
  repack_kernel<<<dim3(4, 3, 64), 256, 0, stream>>>(qkvb, qtb, ktb, vbb);
  attn_mfma_kernel<<<1024, 256, 0, stream>>>(qtb, ktb, vbb, otb);
  pconv_mfma_kernel<true, false, 32><<<dim3(8, 4, B_), 256, 0, stream>>>(
      otb, wo, out_b, x, (void*)out, 256);
}

// Round 5
// 88.323 us; speedup vs baseline: 1.4813x; 1.4813x over previous
//
#include <hip/hip_runtime.h>
#include <hip/hip_bf16.h>

#define B_ 8
#define C_ 256
#define L_ 1024
#define NH_ 8
#define EPS_ 1e-5f

typedef __attribute__((ext_vector_type(8))) short bf16x8;
typedef __attribute__((ext_vector_type(4))) float f32x4;

static __device__ inline ushort f2bf(float f) {
  union { __hip_bfloat16 b; ushort u; } c;
  c.b = __float2bfloat16(f);
  return c.u;
}

// ---------------------------------------------------------------------------
// Kernel W: convert qkv_w [768,256] and out_w [256,256] fp32 -> bf16
// ---------------------------------------------------------------------------
__global__ __launch_bounds__(256) void wconv_kernel(
    const float4* __restrict__ qw, const float4* __restrict__ ow,
    uint2* __restrict__ wq, uint2* __restrict__ wo) {
  int id = blockIdx.x * 256 + threadIdx.x;
  float4 v;
  uint2* dst;
  if (id < 49152) { v = qw[id]; dst = wq + id; }
  else { v = ow[id - 49152]; dst = wo + (id - 49152); }
  union { ushort s[4]; uint2 u; } p;
  p.s[0] = f2bf(v.x); p.s[1] = f2bf(v.y); p.s[2] = f2bf(v.z); p.s[3] = f2bf(v.w);
  *dst = p.u;
}

// ---------------------------------------------------------------------------
// Kernel A: GroupNorm + depthwise conv k=3, output TRANSPOSED bf16 ht[B][L][256]
// ---------------------------------------------------------------------------
__global__ __launch_bounds__(256) void gn_dwconv_kernel(
    const float* __restrict__ x, const float* __restrict__ gamma,
    const float* __restrict__ beta, const float* __restrict__ dw,
    ushort* __restrict__ ht) {
  int blk = blockIdx.x;           // b*32 + g
  int b = blk >> 5, g = blk & 31;
  int t = threadIdx.x;
  __shared__ float hn[8 * L_];
  __shared__ float ws0[4], ws1[4];
  const size_t base = ((size_t)(b * C_ + g * 8)) * L_;

  float s = 0.f, ss = 0.f;
  float vals[32];
#pragma unroll
  for (int i = 0; i < 32; ++i) {
    int e = t + 256 * i;
    float v = x[base + e];
    vals[i] = v;
    s += v; ss += v * v;
  }
#pragma unroll
  for (int off = 32; off >= 1; off >>= 1) {
    s  += __shfl_xor(s, off);
    ss += __shfl_xor(ss, off);
  }
  int wave = t >> 6;
  if ((t & 63) == 0) { ws0[wave] = s; ws1[wave] = ss; }
  __syncthreads();
  s  = ws0[0] + ws0[1] + ws0[2] + ws0[3];
  ss = ws1[0] + ws1[1] + ws1[2] + ws1[3];
  float mean = s * (1.f / 8192.f);
  float var = ss * (1.f / 8192.f) - mean * mean;
  float rstd = rsqrtf(var + EPS_);

#pragma unroll
  for (int i = 0; i < 32; ++i) {
    int e = t + 256 * i;
    int c = g * 8 + (e >> 10);
    float sc = gamma[c] * rstd;
    hn[e] = (vals[i] - mean) * sc + beta[c];
  }
  __syncthreads();
  float r[32];
#pragma unroll
  for (int i = 0; i < 32; ++i) {
    int e = t + 256 * i;
    int l = e & 1023;
    int c = g * 8 + (i >> 2);
    float w0 = dw[c * 3 + 0], w1 = dw[c * 3 + 1], w2 = dw[c * 3 + 2];
    float a = (l > 0) ? hn[e - 1] : 0.f;
    float m = hn[e];
    float z = (l < 1023) ? hn[e + 1] : 0.f;
    r[i] = w0 * a + w1 * m + w2 * z;
  }
#pragma unroll
  for (int li = 0; li < 4; ++li) {
    int l = t + 256 * li;
    union { ushort s8[8]; uint4 u; } pk;
#pragma unroll
    for (int cl = 0; cl < 8; ++cl) pk.s8[cl] = f2bf(r[4 * cl + li]);
    *(uint4*)(ht + ((size_t)(b * L_ + l)) * 256 + g * 8) = pk.u;
  }
}

// ---------------------------------------------------------------------------
// Kernel B/D: pointwise conv via MFMA. M=l, N=oc, K=c(256).
// ---------------------------------------------------------------------------
template <bool RESID, bool BF16OUT, int OCT>
__global__ __launch_bounds__(256) void pconv_mfma_kernel(
    const ushort* __restrict__ Xt, const ushort* __restrict__ Wb,
    const float* __restrict__ bias, const float* __restrict__ resid,
    void* __restrict__ outv, int OC) {
  constexpr int NN = OCT / 16;
  int b = blockIdx.z;
  int t = threadIdx.x;
  int w = t >> 6, l = t & 63;
  int g = l >> 4, ln = l & 15;
  int wl = w >> 1, wo = w & 1;
  int lbase = blockIdx.x * 128 + wl * 64;
  int ocbase = blockIdx.y * (2 * OCT) + wo * OCT;

  const ushort* xp = Xt + ((size_t)b * L_ + lbase) * 256;
  const ushort* wp = Wb + (size_t)ocbase * 256;

  f32x4 acc[4][NN];
#pragma unroll
  for (int ml = 0; ml < 4; ++ml)
#pragma unroll
    for (int nn = 0; nn < NN; ++nn) acc[ml][nn] = (f32x4){0.f, 0.f, 0.f, 0.f};

  for (int c0 = 0; c0 < 256; c0 += 32) {
    bf16x8 af[4], bf[NN];
#pragma unroll
    for (int ml = 0; ml < 4; ++ml)
      af[ml] = *(const bf16x8*)(xp + (size_t)(16 * ml + ln) * 256 + c0 + 8 * g);
#pragma unroll
    for (int nn = 0; nn < NN; ++nn)
      bf[nn] = *(const bf16x8*)(wp + (size_t)(16 * nn + ln) * 256 + c0 + 8 * g);
#pragma unroll
    for (int ml = 0; ml < 4; ++ml)
#pragma unroll
      for (int nn = 0; nn < NN; ++nn)
        acc[ml][nn] = __builtin_amdgcn_mfma_f32_16x16x32_bf16(af[ml], bf[nn], acc[ml][nn], 0, 0, 0);
  }

#pragma unroll
  for (int nn = 0; nn < NN; ++nn) {
    int oc = ocbase + 16 * nn + ln;
    float bs = bias[oc];
#pragma unroll
    for (int ml = 0; ml < 4; ++ml) {
      int lr = lbase + 16 * ml + 4 * g;
      size_t ob = ((size_t)b * OC + oc) * L_ + lr;
      float rv[4];
#pragma unroll
      for (int r4 = 0; r4 < 4; ++r4) rv[r4] = acc[ml][nn][r4] + bs;
      if (RESID) {
        float4 rd = *(const float4*)(resid + ob);
        rv[0] += rd.x; rv[1] += rd.y; rv[2] += rd.z; rv[3] += rd.w;
      }
      if (BF16OUT) {
        union { ushort s[4]; uint2 u; } pk;
#pragma unroll
        for (int r4 = 0; r4 < 4; ++r4) pk.s[r4] = f2bf(rv[r4]);
        *(uint2*)((ushort*)outv + ob) = pk.u;
      } else {
        float4 st = make_float4(rv[0], rv[1], rv[2], rv[3]);
        *(float4*)((float*)outv + ob) = st;
      }
    }
  }
}

// ---------------------------------------------------------------------------
// Repack: qkvb [B,768,L] bf16 -> qt,kt [bh][L][32] (transposed), vb [bh][32][L]
// ---------------------------------------------------------------------------
__global__ __launch_bounds__(256) void repack_kernel(
    const ushort* __restrict__ qkvb, ushort* __restrict__ qt,
    ushort* __restrict__ kt, ushort* __restrict__ vb) {
  int l0 = blockIdx.x * 256;
  int kind = blockIdx.y;
  int bh = blockIdx.z;
  int b = bh >> 3, hh = bh & 7;
  int t = threadIdx.x;
  const ushort* src = qkvb + ((size_t)(b * 768 + hh * 96 + kind * 32)) * L_;
  int colu = t & 127, rhalf = t >> 7;

  if (kind == 2) {
    const uint* su = (const uint*)src;
    uint* du = (uint*)(vb + (size_t)bh * 32 * L_);
#pragma unroll
    for (int it = 0; it < 16; ++it) {
      int d = it * 2 + rhalf;
      int idx = d * 512 + l0 / 2 + colu;
      du[idx] = su[idx];
    }
  } else {
    __shared__ ushort tile[32][264];
    const uint* su = (const uint*)src;
#pragma unroll
    for (int it = 0; it < 16; ++it) {
      int d = it * 2 + rhalf;
      uint v = su[d * 512 + l0 / 2 + colu];
      tile[d][2 * colu] = (ushort)(v & 0xffff);
      tile[d][2 * colu + 1] = (ushort)(v >> 16);
    }
    __syncthreads();
    ushort* dst = (kind ? kt : qt) + (size_t)bh * L_ * 32;
    uint outv[16];
#pragma unroll
    for (int d2 = 0; d2 < 16; ++d2)
      outv[d2] = (uint)tile[2 * d2][t] | ((uint)tile[2 * d2 + 1][t] << 16);
    uint4* dp = (uint4*)(dst + (size_t)(l0 + t) * 32);
    dp[0] = make_uint4(outv[0], outv[1], outv[2], outv[3]);
    dp[1] = make_uint4(outv[4], outv[5], outv[6], outv[7]);
    dp[2] = make_uint4(outv[8], outv[9], outv[10], outv[11]);
    dp[3] = make_uint4(outv[12], outv[13], outv[14], outv[15]);
  }
}

// ---------------------------------------------------------------------------
// Kernel C: MFMA flash attention, block-shared double-buffered LDS staging.
// Block = 4 waves x 32q = 128 q. kv-tile 128. grid 512 blocks.
// K_lds [128][32] with 16B-slot ^ (row&3); V_lds [32][128] with 8B-slot ^
// ((row&3)<<2). Stage via regs (load-early / write-late), 1 barrier per tile.
// ---------------------------------------------------------------------------
__global__ __launch_bounds__(256) void attn_mfma_kernel(
    const ushort* __restrict__ qt, const ushort* __restrict__ kt,
    const ushort* __restrict__ vb, ushort* __restrict__ ot) {
  const int id = blockIdx.x;
  // bijective XCD swizzle: bh fixed by id&7 -> all 8 q-tiles of bh on one XCD
  const int bh = ((id & 7) << 3) | (id >> 6);
  const int qtile = (id >> 3) & 7;
  const int b = bh >> 3, hh = bh & 7;
  const int t = threadIdx.x;
  const int w = t >> 6, l = t & 63;
  const int g = l >> 4, ln = l & 15;
  const int q0b = qtile * 128;
  const int q0 = q0b + w * 32;

  __shared__ ushort Kl[2][128 * 32];          // 2 x 8 KB
  __shared__ ushort Vl[2][32 * 128];          // 2 x 8 KB
  __shared__ __align__(16) ushort otile[128][40];

  const ushort* qbase = qt + (size_t)bh * (L_ * 32);
  const ushort* kbase = kt + (size_t)bh * (L_ * 32);
  const ushort* vbase = vb + (size_t)bh * (32 * L_);

  // ---- staging geometry (per thread) ----
  const int krow = t >> 1;                    // 0..127
  const int ks16 = 2 * (t & 1);               // 16B slots {ks16, ks16+1}
  const ushort* kg = kbase + (size_t)krow * 32 + ks16 * 8;
  const int kw0 = krow * 32 + ((ks16 ^ (krow & 3)) * 8);
  const int kw1 = krow * 32 + (((ks16 + 1) ^ (krow & 3)) * 8);

  const int vrow = t >> 3;                    // 0..31
  const int vs16 = 2 * (t & 7);               // 16B slots {vs16, vs16+1}
  const ushort* vg = vbase + (size_t)vrow * L_ + vs16 * 8;
  const int vw0 = vrow * 128 + ((vs16 ^ ((vrow & 3) << 1)) * 8);
  const int vw1 = vrow * 128 + (((vs16 + 1) ^ ((vrow & 3) << 1)) * 8);

  // ---- fragment-read geometry ----
  const int kread = (g ^ (ln & 3)) * 8;       // K 16B slot, row&3 == ln&3
  const int e2 = (ln & 3) << 2;               // V 8B-slot xor

  const f32x4 z4 = {0.f, 0.f, 0.f, 0.f};
  bf16x8 bq[2];
  bq[0] = *(const bf16x8*)(qbase + (size_t)(q0 + ln) * 32 + g * 8);
  bq[1] = *(const bf16x8*)(qbase + (size_t)(q0 + 16 + ln) * 32 + g * 8);

  union { ushort s[8]; bf16x8 v; } onesu;
#pragma unroll
  for (int i = 0; i < 8; ++i) onesu.s[i] = 0x3F80;  // bf16 1.0
  const bf16x8 ones = onesu.v;

  f32x4 oacc[2][2];  // [md][nq]
  oacc[0][0] = z4; oacc[0][1] = z4; oacc[1][0] = z4; oacc[1][1] = z4;
  f32x4 oaccS[2] = {z4, z4};
  float M[2] = {-3e38f, -3e38f};
  const float cs = 0.0625f * 1.44269504f;     // scale * log2(e)

  // ---- prologue: stage tile 0 ----
  uint4 ka0, ka1, va0, va1;
  ka0 = *(const uint4*)kg;       ka1 = *(const uint4*)(kg + 8);
  va0 = *(const uint4*)vg;       va1 = *(const uint4*)(vg + 8);
  __builtin_amdgcn_sched_barrier(0);
  *(uint4*)&Kl[0][kw0] = ka0;    *(uint4*)&Kl[0][kw1] = ka1;
  *(uint4*)&Vl[0][vw0] = va0;    *(uint4*)&Vl[0][vw1] = va1;
  asm volatile("s_waitcnt lgkmcnt(0)" ::: "memory");
  __builtin_amdgcn_s_barrier();
  __builtin_amdgcn_sched_barrier(0);

  for (int tt = 0; tt < 8; ++tt) {
    const int cur = tt & 1;
    // issue next tile's global loads early (latency hides under compute)
    if (tt < 7) {
      ka0 = *(const uint4*)(kg + (tt + 1) * 4096);
      ka1 = *(const uint4*)(kg + (tt + 1) * 4096 + 8);
      va0 = *(const uint4*)(vg + (tt + 1) * 128);
      va1 = *(const uint4*)(vg + (tt + 1) * 128 + 8);
    }
    __builtin_amdgcn_sched_barrier(0);

    const ushort* Kc = &Kl[cur][0];
    const ushort* Vc = &Vl[cur][0];

    // ---- QK^T ----
    f32x4 sacc[8][2];
#pragma unroll
    for (int mk = 0; mk < 8; ++mk) {
      bf16x8 ak = *(const bf16x8*)(Kc + (16 * mk + ln) * 32 + kread);
      sacc[mk][0] = __builtin_amdgcn_mfma_f32_16x16x32_bf16(ak, bq[0], z4, 0, 0, 0);
      sacc[mk][1] = __builtin_amdgcn_mfma_f32_16x16x32_bf16(ak, bq[1], z4, 0, 0, 0);
    }

    // ---- online softmax per nq ----
    uint upk[2][8][2];
#pragma unroll
    for (int nq = 0; nq < 2; ++nq) {
      float mx[8];
#pragma unroll
      for (int mk = 0; mk < 8; ++mk)
        mx[mk] = fmaxf(fmaxf(sacc[mk][nq][0], sacc[mk][nq][1]),
                       fmaxf(sacc[mk][nq][2], sacc[mk][nq][3]));
      float a0 = fmaxf(mx[0], mx[1]), a1 = fmaxf(mx[2], mx[3]);
      float a2 = fmaxf(mx[4], mx[5]), a3 = fmaxf(mx[6], mx[7]);
      float mt = fmaxf(fmaxf(a0, a1), fmaxf(a2, a3));
      mt = fmaxf(mt, __shfl_xor(mt, 16));
      mt = fmaxf(mt, __shfl_xor(mt, 32));

      if (!__all((mt - M[nq]) * cs <= 8.f)) {
        float Mn = fmaxf(M[nq], mt);
        float corr = exp2f((M[nq] - Mn) * cs);
#pragma unroll
        for (int r = 0; r < 4; ++r) {
          oacc[0][nq][r] *= corr; oacc[1][nq][r] *= corr; oaccS[nq][r] *= corr;
        }
        M[nq] = Mn;
      }
      float em = M[nq] * cs;
#pragma unroll
      for (int mk = 0; mk < 8; ++mk) {
#pragma unroll
        for (int r = 0; r < 4; ++r)
          sacc[mk][nq][r] = exp2f(sacc[mk][nq][r] * cs - em);
        uint u0, u1;
        asm("v_cvt_pk_bf16_f32 %0, %1, %2" : "=v"(u0) : "v"(sacc[mk][nq][0]), "v"(sacc[mk][nq][1]));
        asm("v_cvt_pk_bf16_f32 %0, %1, %2" : "=v"(u1) : "v"(sacc[mk][nq][2]), "v"(sacc[mk][nq][3]));
        upk[nq][mk][0] = u0; upk[nq][mk][1] = u1;
      }
    }

    // ---- PV + denominator ----
#pragma unroll
    for (int ks = 0; ks < 4; ++ks) {
      union { uint u[4]; bf16x8 v; } pb0, pb1;
      pb0.u[0] = upk[0][2 * ks][0]; pb0.u[1] = upk[0][2 * ks][1];
      pb0.u[2] = upk[0][2 * ks + 1][0]; pb0.u[3] = upk[0][2 * ks + 1][1];
      pb1.u[0] = upk[1][2 * ks][0]; pb1.u[1] = upk[1][2 * ks][1];
      pb1.u[2] = upk[1][2 * ks + 1][0]; pb1.u[3] = upk[1][2 * ks + 1][1];
      oaccS[0] = __builtin_amdgcn_mfma_f32_16x16x32_bf16(ones, pb0.v, oaccS[0], 0, 0, 0);
      oaccS[1] = __builtin_amdgcn_mfma_f32_16x16x32_bf16(ones, pb1.v, oaccS[1], 0, 0, 0);
      const int s0 = ((8 * ks + g) ^ e2) * 4;
#pragma unroll
      for (int md = 0; md < 2; ++md) {
        const int rb = (16 * md + ln) * 128;
        uint2 lo = *(const uint2*)(Vc + rb + s0);
        uint2 hi = *(const uint2*)(Vc + rb + (s0 ^ 16));
        union { uint u[4]; bf16x8 v; } av;
        av.u[0] = lo.x; av.u[1] = lo.y; av.u[2] = hi.x; av.u[3] = hi.y;
        oacc[md][0] = __builtin_amdgcn_mfma_f32_16x16x32_bf16(av.v, pb0.v, oacc[md][0], 0, 0, 0);
        oacc[md][1] = __builtin_amdgcn_mfma_f32_16x16x32_bf16(av.v, pb1.v, oacc[md][1], 0, 0, 0);
      }
    }

    __builtin_amdgcn_sched_barrier(0);
    // ---- write staged regs -> LDS (next buffer), single barrier ----
    if (tt < 7) {
      const int nxt = cur ^ 1;
      *(uint4*)&Kl[nxt][kw0] = ka0;  *(uint4*)&Kl[nxt][kw1] = ka1;
      *(uint4*)&Vl[nxt][vw0] = va0;  *(uint4*)&Vl[nxt][vw1] = va1;
      asm volatile("s_waitcnt lgkmcnt(0)" ::: "memory");
      __builtin_amdgcn_s_barrier();
      __builtin_amdgcn_sched_barrier(0);
    }
  }

  // ---- epilogue: normalize, LDS transpose, write ot[B][L][256] ----
  float rl0 = 1.f / oaccS[0][0];
  float rl1 = 1.f / oaccS[1][0];
#pragma unroll
  for (int md = 0; md < 2; ++md) {
    ushort4 p0, p1;
    p0.x = f2bf(oacc[md][0][0] * rl0); p0.y = f2bf(oacc[md][0][1] * rl0);
    p0.z = f2bf(oacc[md][0][2] * rl0); p0.w = f2bf(oacc[md][0][3] * rl0);
    p1.x = f2bf(oacc[md][1][0] * rl1); p1.y = f2bf(oacc[md][1][1] * rl1);
    p1.z = f2bf(oacc[md][1][2] * rl1); p1.w = f2bf(oacc[md][1][3] * rl1);
    *(ushort4*)&otile[w * 32 + ln][16 * md + 4 * g] = p0;
    *(ushort4*)&otile[w * 32 + 16 + ln][16 * md + 4 * g] = p1;
  }
  __syncthreads();
  {
    int row = t >> 1, half = t & 1;
    uint4 v0 = *(const uint4*)&otile[row][half * 16];
    uint4 v1 = *(const uint4*)&otile[row][half * 16 + 8];
    ushort* dstp = ot + ((size_t)(b * L_ + q0b + row)) * 256 + hh * 32 + half * 16;
    *(uint4*)dstp = v0;
    *(uint4*)(dstp + 8) = v1;
  }
}

// ---------------------------------------------------------------------------
extern "C" void kernel_launch(void* const* d_in, const int* in_sizes, int n_in,
                              void* d_out, int out_size, void* d_ws, size_t ws_size,
                              hipStream_t stream) {
  const float* x      = (const float*)d_in[0];
  const float* gamma  = (const float*)d_in[1];
  const float* beta   = (const float*)d_in[2];
  const float* dw     = (const float*)d_in[3];
  const float* qkv_w  = (const float*)d_in[4];
  const float* qkv_b  = (const float*)d_in[5];
  const float* out_w  = (const float*)d_in[6];
  const float* out_b  = (const float*)d_in[7];
  float* out = (float*)d_out;

  char* ws = (char*)d_ws;
  ushort* ht   = (ushort*)(ws);                   // 4 MiB @0  (dead after qkv)
  ushort* qkvb = (ushort*)(ws + (4u << 20));      // 12 MiB @4 (dead after repack)
  ushort* qtb  = (ushort*)(ws + (16u << 20));     // 4 MiB @16
  ushort* ktb  = (ushort*)(ws + (20u << 20));     // 4 MiB @20
  ushort* vbb  = (ushort*)(ws + (24u << 20));     // 4 MiB @24
  ushort* otb  = (ushort*)(ws);                   // 4 MiB @0  (reuse ht)
  ushort* wq   = (ushort*)(ws + (28u << 20));     // 384 KiB @28M
  ushort* wo   = (ushort*)(ws + (28u << 20) + (512u << 10));  // 128 KiB

  wconv_kernel<<<256, 256, 0, stream>>>((const float4*)qkv_w, (const float4*)out_w,
                                        (uint2*)wq, (uint2*)wo);
  gn_dwconv_kernel<<<B_ * 32, 256, 0, stream>>>(x, gamma, beta, dw, ht);
  pconv_mfma_kernel<false, true, 64><<<dim3(8, 6, B_), 256, 0, stream>>>(
      ht, wq, qkv_b, nullptr, (void*)qkvb, 768);
  repack_kernel<<<dim3(4, 3, 64), 256, 0, stream>>>(qkvb, qtb, ktb, vbb);
  attn_mfma_kernel<<<512, 256, 0, stream>>>(qtb, ktb, vbb, otb);
  pconv_mfma_kernel<true, false, 32><<<dim3(8, 4, B_), 256, 0, stream>>>(
      otb, wo, out_b, x, (void*)out, 256);
}

// Round 6
// 72.837 us; speedup vs baseline: 1.7963x; 1.2126x over previous
//
#include <hip/hip_runtime.h>
#include <hip/hip_bf16.h>

#define B_ 8
#define C_ 256
#define L_ 1024
#define NH_ 8
#define EPS_ 1e-5f

typedef __attribute__((ext_vector_type(8))) short bf16x8;
typedef __attribute__((ext_vector_type(4))) float f32x4;

static __device__ inline ushort f2bf(float f) {
  union { __hip_bfloat16 b; ushort u; } c;
  c.b = __float2bfloat16(f);
  return c.u;
}

// ---------------------------------------------------------------------------
// Kernel A: blocks 0-255: weight fp32->bf16 convert; blocks 256-511:
// GroupNorm + depthwise conv k=3, output TRANSPOSED bf16 ht[B][L][256]
// ---------------------------------------------------------------------------
__global__ __launch_bounds__(256) void gnw_kernel(
    const float* __restrict__ x, const float* __restrict__ gamma,
    const float* __restrict__ beta, const float* __restrict__ dw,
    const float4* __restrict__ qw, const float4* __restrict__ ow,
    uint2* __restrict__ wq, uint2* __restrict__ wo_,
    ushort* __restrict__ ht) {
  __shared__ float hn[8 * L_];
  __shared__ float ws0[4], ws1[4];
  int t = threadIdx.x;
  if (blockIdx.x < 256) {
    int id = blockIdx.x * 256 + t;
    float4 v;
    uint2* dst;
    if (id < 49152) { v = qw[id]; dst = wq + id; }
    else { v = ow[id - 49152]; dst = wo_ + (id - 49152); }
    union { ushort s[4]; uint2 u; } p;
    p.s[0] = f2bf(v.x); p.s[1] = f2bf(v.y); p.s[2] = f2bf(v.z); p.s[3] = f2bf(v.w);
    *dst = p.u;
    return;
  }
  int blk = blockIdx.x - 256;     // b*32 + g
  int b = blk >> 5, g = blk & 31;
  const size_t base = ((size_t)(b * C_ + g * 8)) * L_;

  float s = 0.f, ss = 0.f;
  float vals[32];
#pragma unroll
  for (int i = 0; i < 32; ++i) {
    int e = t + 256 * i;
    float v = x[base + e];
    vals[i] = v;
    s += v; ss += v * v;
  }
#pragma unroll
  for (int off = 32; off >= 1; off >>= 1) {
    s  += __shfl_xor(s, off);
    ss += __shfl_xor(ss, off);
  }
  int wave = t >> 6;
  if ((t & 63) == 0) { ws0[wave] = s; ws1[wave] = ss; }
  __syncthreads();
  s  = ws0[0] + ws0[1] + ws0[2] + ws0[3];
  ss = ws1[0] + ws1[1] + ws1[2] + ws1[3];
  float mean = s * (1.f / 8192.f);
  float var = ss * (1.f / 8192.f) - mean * mean;
  float rstd = rsqrtf(var + EPS_);

#pragma unroll
  for (int i = 0; i < 32; ++i) {
    int e = t + 256 * i;
    int c = g * 8 + (e >> 10);
    float sc = gamma[c] * rstd;
    hn[e] = (vals[i] - mean) * sc + beta[c];
  }
  __syncthreads();
  float r[32];
#pragma unroll
  for (int i = 0; i < 32; ++i) {
    int e = t + 256 * i;
    int l = e & 1023;
    int c = g * 8 + (i >> 2);
    float w0 = dw[c * 3 + 0], w1 = dw[c * 3 + 1], w2 = dw[c * 3 + 2];
    float a = (l > 0) ? hn[e - 1] : 0.f;
    float m = hn[e];
    float z = (l < 1023) ? hn[e + 1] : 0.f;
    r[i] = w0 * a + w1 * m + w2 * z;
  }
#pragma unroll
  for (int li = 0; li < 4; ++li) {
    int l = t + 256 * li;
    union { ushort s8[8]; uint4 u; } pk;
#pragma unroll
    for (int cl = 0; cl < 8; ++cl) pk.s8[cl] = f2bf(r[4 * cl + li]);
    *(uint4*)(ht + ((size_t)(b * L_ + l)) * 256 + g * 8) = pk.u;
  }
}

// ---------------------------------------------------------------------------
// Kernel B: qkv pointwise conv via MFMA, fused repack epilogue.
// Block = 128 l x 96 oc (one head: q32|k32|v32). grid (8 ltile, 8 head, 8 b).
// 4 waves = 2(l) x 2(oc half of 96 -> 48 = 3 frags). Writes qt/kt [bh][L][32]
// and PI-permuted vb [bh][32][L] directly.
// ---------------------------------------------------------------------------
__global__ __launch_bounds__(256) void qkv_fused_kernel(
    const ushort* __restrict__ Xt, const ushort* __restrict__ Wb,
    const float* __restrict__ bias, ushort* __restrict__ qt,
    ushort* __restrict__ kt, ushort* __restrict__ vb) {
  int bx = blockIdx.x, head = blockIdx.y, b = blockIdx.z;
  int bh = b * 8 + head;
  int t = threadIdx.x;
  int w = t >> 6, l = t & 63;
  int g = l >> 4, ln = l & 15;
  int wl = w >> 1, wo = w & 1;
  int lbase = bx * 128 + wl * 64;

  const ushort* xp = Xt + ((size_t)b * L_ + lbase) * 256;
  const ushort* wp = Wb + (size_t)(head * 96 + wo * 48) * 256;

  f32x4 acc[4][3];
#pragma unroll
  for (int ml = 0; ml < 4; ++ml)
#pragma unroll
    for (int nn = 0; nn < 3; ++nn) acc[ml][nn] = (f32x4){0.f, 0.f, 0.f, 0.f};

  for (int c0 = 0; c0 < 256; c0 += 32) {
    bf16x8 af[4], bf[3];
#pragma unroll
    for (int ml = 0; ml < 4; ++ml)
      af[ml] = *(const bf16x8*)(xp + (size_t)(16 * ml + ln) * 256 + c0 + 8 * g);
#pragma unroll
    for (int nn = 0; nn < 3; ++nn)
      bf[nn] = *(const bf16x8*)(wp + (size_t)(16 * nn + ln) * 256 + c0 + 8 * g);
#pragma unroll
    for (int ml = 0; ml < 4; ++ml)
#pragma unroll
      for (int nn = 0; nn < 3; ++nn)
        acc[ml][nn] = __builtin_amdgcn_mfma_f32_16x16x32_bf16(af[ml], bf[nn], acc[ml][nn], 0, 0, 0);
  }

  // bias
#pragma unroll
  for (int nn = 0; nn < 3; ++nn) {
    float bs = bias[head * 96 + wo * 48 + 16 * nn + ln];
#pragma unroll
    for (int ml = 0; ml < 4; ++ml)
#pragma unroll
      for (int r = 0; r < 4; ++r) acc[ml][nn][r] += bs;
  }

  __shared__ ushort tr[5120];

  // rounds 0 (q), 1 (k): transpose to [l][d] (pad 40), write [bh][l][32]
  for (int rk = 0; rk < 2; ++rk) {
    __syncthreads();
#pragma unroll
    for (int nn = 0; nn < 3; ++nn) {
      int ocl0 = wo * 48 + 16 * nn;
      if (ocl0 >= rk * 32 && ocl0 < rk * 32 + 32) {
        int d = ocl0 - rk * 32 + ln;
#pragma unroll
        for (int ml = 0; ml < 4; ++ml) {
          int lrow = wl * 64 + 16 * ml + 4 * g;
#pragma unroll
          for (int r = 0; r < 4; ++r)
            tr[(lrow + r) * 40 + d] = f2bf(acc[ml][nn][r]);
        }
      }
    }
    __syncthreads();
    {
      int row = t >> 1, half = t & 1;
      uint4 v0 = *(const uint4*)&tr[row * 40 + half * 16];
      uint4 v1 = *(const uint4*)&tr[row * 40 + half * 16 + 8];
      ushort* dst = (rk ? kt : qt) +
                    ((size_t)bh * L_ + bx * 128 + row) * 32 + half * 16;
      *(uint4*)dst = v0;
      *(uint4*)(dst + 8) = v1;
    }
  }

  // round 2 (v): [d][l] (pad 136), PI-permute on global write
  __syncthreads();
  if (wo == 1) {
#pragma unroll
    for (int nn = 1; nn < 3; ++nn) {
      int d = 16 * (nn - 1) + ln;
#pragma unroll
      for (int ml = 0; ml < 4; ++ml) {
        int lc = wl * 64 + 16 * ml + 4 * g;
        union { ushort s[4]; uint2 u; } pk;
#pragma unroll
        for (int r = 0; r < 4; ++r) pk.s[r] = f2bf(acc[ml][nn][r]);
        *(uint2*)&tr[d * 136 + lc] = pk.u;
      }
    }
  }
  __syncthreads();
  {
    int d = t >> 3, s0 = t & 7;
    ushort* vdst = vb + ((size_t)bh * 32 + d) * L_ + bx * 128;
#pragma unroll
    for (int c = 0; c < 2; ++c) {
      int ch = s0 + 8 * c;
      int jj = ch >> 2, gg = ch & 3;
      uint2 lo = *(const uint2*)&tr[d * 136 + 32 * jj + 4 * gg];
      uint2 hi = *(const uint2*)&tr[d * 136 + 32 * jj + 16 + 4 * gg];
      *(uint4*)(vdst + 32 * jj + 8 * gg) = make_uint4(lo.x, lo.y, hi.x, hi.y);
    }
  }
}

// ---------------------------------------------------------------------------
// Kernel D: out pointwise conv via MFMA + residual (fp32 out).
// ---------------------------------------------------------------------------
template <int OCT>
__global__ __launch_bounds__(256) void pconv_mfma_kernel(
    const ushort* __restrict__ Xt, const ushort* __restrict__ Wb,
    const float* __restrict__ bias, const float* __restrict__ resid,
    float* __restrict__ out, int OC) {
  constexpr int NN = OCT / 16;
  int b = blockIdx.z;
  int t = threadIdx.x;
  int w = t >> 6, l = t & 63;
  int g = l >> 4, ln = l & 15;
  int wl = w >> 1, wo = w & 1;
  int lbase = blockIdx.x * 128 + wl * 64;
  int ocbase = blockIdx.y * (2 * OCT) + wo * OCT;

  const ushort* xp = Xt + ((size_t)b * L_ + lbase) * 256;
  const ushort* wp = Wb + (size_t)ocbase * 256;

  f32x4 acc[4][NN];
#pragma unroll
  for (int ml = 0; ml < 4; ++ml)
#pragma unroll
    for (int nn = 0; nn < NN; ++nn) acc[ml][nn] = (f32x4){0.f, 0.f, 0.f, 0.f};

  for (int c0 = 0; c0 < 256; c0 += 32) {
    bf16x8 af[4], bf[NN];
#pragma unroll
    for (int ml = 0; ml < 4; ++ml)
      af[ml] = *(const bf16x8*)(xp + (size_t)(16 * ml + ln) * 256 + c0 + 8 * g);
#pragma unroll
    for (int nn = 0; nn < NN; ++nn)
      bf[nn] = *(const bf16x8*)(wp + (size_t)(16 * nn + ln) * 256 + c0 + 8 * g);
#pragma unroll
    for (int ml = 0; ml < 4; ++ml)
#pragma unroll
      for (int nn = 0; nn < NN; ++nn)
        acc[ml][nn] = __builtin_amdgcn_mfma_f32_16x16x32_bf16(af[ml], bf[nn], acc[ml][nn], 0, 0, 0);
  }

#pragma unroll
  for (int nn = 0; nn < NN; ++nn) {
    int oc = ocbase + 16 * nn + ln;
    float bs = bias[oc];
#pragma unroll
    for (int ml = 0; ml < 4; ++ml) {
      int lr = lbase + 16 * ml + 4 * g;
      size_t ob = ((size_t)b * OC + oc) * L_ + lr;
      float4 rd = *(const float4*)(resid + ob);
      float4 st = make_float4(acc[ml][nn][0] + bs + rd.x, acc[ml][nn][1] + bs + rd.y,
                              acc[ml][nn][2] + bs + rd.z, acc[ml][nn][3] + bs + rd.w);
      *(float4*)(out + ob) = st;
    }
  }
}

// ---------------------------------------------------------------------------
// Kernel C: MFMA flash attention, dbuf LDS staging, conflict-free layouts:
// K [128][40] padded; V PI-permuted [32][136] padded, b128 fragment reads.
// Block = 4 waves x 32q. grid 512. Output ot[B][L][256] bf16.
// ---------------------------------------------------------------------------
__global__ __launch_bounds__(256) void attn_mfma_kernel(
    const ushort* __restrict__ qt, const ushort* __restrict__ kt,
    const ushort* __restrict__ vb, ushort* __restrict__ ot) {
  const int id = blockIdx.x;
  const int bh = ((id & 7) << 3) | (id >> 6);
  const int qtile = (id >> 3) & 7;
  const int b = bh >> 3, hh = bh & 7;
  const int t = threadIdx.x;
  const int w = t >> 6, l = t & 63;
  const int g = l >> 4, ln = l & 15;
  const int q0b = qtile * 128;
  const int q0 = q0b + w * 32;

  __shared__ ushort Kl[2][128 * 40];          // padded rows: 80B stride
  __shared__ ushort Vl[2][32 * 136];          // padded rows: 272B stride
  __shared__ __align__(16) ushort otile[128][40];

  const ushort* qbase = qt + (size_t)bh * (L_ * 32);
  const ushort* kbase = kt + (size_t)bh * (L_ * 32);
  const ushort* vbase = vb + (size_t)bh * (32 * L_);

  // staging geometry
  const int krow = t >> 1, khalf = t & 1;
  const ushort* kg = kbase + krow * 32 + khalf * 16;
  const int kwo = krow * 40 + khalf * 16;
  const int vrow = t >> 3, vc = (t & 7) * 16;
  const ushort* vg = vbase + (size_t)vrow * L_ + vc;
  const int vwo = vrow * 136 + vc;

  const f32x4 z4 = {0.f, 0.f, 0.f, 0.f};
  bf16x8 bq[2];
  bq[0] = *(const bf16x8*)(qbase + (size_t)(q0 + ln) * 32 + g * 8);
  bq[1] = *(const bf16x8*)(qbase + (size_t)(q0 + 16 + ln) * 32 + g * 8);

  union { ushort s[8]; bf16x8 v; } onesu;
#pragma unroll
  for (int i = 0; i < 8; ++i) onesu.s[i] = 0x3F80;  // bf16 1.0
  const bf16x8 ones = onesu.v;

  f32x4 oacc[2][2];  // [md][nq]
  oacc[0][0] = z4; oacc[0][1] = z4; oacc[1][0] = z4; oacc[1][1] = z4;
  f32x4 oaccS[2] = {z4, z4};
  float M[2] = {-3e38f, -3e38f};
  const float cs = 0.0625f * 1.44269504f;     // scale * log2(e)

  // prologue: stage tile 0
  uint4 ka0, ka1, va0, va1;
  ka0 = *(const uint4*)kg;       ka1 = *(const uint4*)(kg + 8);
  va0 = *(const uint4*)vg;       va1 = *(const uint4*)(vg + 8);
  __builtin_amdgcn_sched_barrier(0);
  *(uint4*)&Kl[0][kwo] = ka0;    *(uint4*)&Kl[0][kwo + 8] = ka1;
  *(uint4*)&Vl[0][vwo] = va0;    *(uint4*)&Vl[0][vwo + 8] = va1;
  asm volatile("s_waitcnt lgkmcnt(0)" ::: "memory");
  __builtin_amdgcn_s_barrier();
  __builtin_amdgcn_sched_barrier(0);

  for (int tt = 0; tt < 8; ++tt) {
    const int cur = tt & 1;
    if (tt < 7) {
      ka0 = *(const uint4*)(kg + (tt + 1) * 4096);
      ka1 = *(const uint4*)(kg + (tt + 1) * 4096 + 8);
      va0 = *(const uint4*)(vg + (tt + 1) * 128);
      va1 = *(const uint4*)(vg + (tt + 1) * 128 + 8);
    }
    __builtin_amdgcn_sched_barrier(0);

    const ushort* Kc = &Kl[cur][0];
    const ushort* Vc = &Vl[cur][0];

    // QK^T
    f32x4 sacc[8][2];
#pragma unroll
    for (int mk = 0; mk < 8; ++mk) {
      bf16x8 ak = *(const bf16x8*)(Kc + (16 * mk + ln) * 40 + g * 8);
      sacc[mk][0] = __builtin_amdgcn_mfma_f32_16x16x32_bf16(ak, bq[0], z4, 0, 0, 0);
      sacc[mk][1] = __builtin_amdgcn_mfma_f32_16x16x32_bf16(ak, bq[1], z4, 0, 0, 0);
    }

    // online softmax per nq
    uint upk[2][8][2];
#pragma unroll
    for (int nq = 0; nq < 2; ++nq) {
      float mx[8];
#pragma unroll
      for (int mk = 0; mk < 8; ++mk)
        mx[mk] = fmaxf(fmaxf(sacc[mk][nq][0], sacc[mk][nq][1]),
                       fmaxf(sacc[mk][nq][2], sacc[mk][nq][3]));
      float a0 = fmaxf(mx[0], mx[1]), a1 = fmaxf(mx[2], mx[3]);
      float a2 = fmaxf(mx[4], mx[5]), a3 = fmaxf(mx[6], mx[7]);
      float mt = fmaxf(fmaxf(a0, a1), fmaxf(a2, a3));
      mt = fmaxf(mt, __shfl_xor(mt, 16));
      mt = fmaxf(mt, __shfl_xor(mt, 32));

      if (!__all((mt - M[nq]) * cs <= 8.f)) {
        float Mn = fmaxf(M[nq], mt);
        float corr = exp2f((M[nq] - Mn) * cs);
#pragma unroll
        for (int r = 0; r < 4; ++r) {
          oacc[0][nq][r] *= corr; oacc[1][nq][r] *= corr; oaccS[nq][r] *= corr;
        }
        M[nq] = Mn;
      }
      float em = M[nq] * cs;
#pragma unroll
      for (int mk = 0; mk < 8; ++mk) {
#pragma unroll
        for (int r = 0; r < 4; ++r)
          sacc[mk][nq][r] = exp2f(sacc[mk][nq][r] * cs - em);
        uint u0, u1;
        asm("v_cvt_pk_bf16_f32 %0, %1, %2" : "=v"(u0) : "v"(sacc[mk][nq][0]), "v"(sacc[mk][nq][1]));
        asm("v_cvt_pk_bf16_f32 %0, %1, %2" : "=v"(u1) : "v"(sacc[mk][nq][2]), "v"(sacc[mk][nq][3]));
        upk[nq][mk][0] = u0; upk[nq][mk][1] = u1;
      }
    }

    // PV + denominator
#pragma unroll
    for (int ks = 0; ks < 4; ++ks) {
      union { uint u[4]; bf16x8 v; } pb0, pb1;
      pb0.u[0] = upk[0][2 * ks][0]; pb0.u[1] = upk[0][2 * ks][1];
      pb0.u[2] = upk[0][2 * ks + 1][0]; pb0.u[3] = upk[0][2 * ks + 1][1];
      pb1.u[0] = upk[1][2 * ks][0]; pb1.u[1] = upk[1][2 * ks][1];
      pb1.u[2] = upk[1][2 * ks + 1][0]; pb1.u[3] = upk[1][2 * ks + 1][1];
      oaccS[0] = __builtin_amdgcn_mfma_f32_16x16x32_bf16(ones, pb0.v, oaccS[0], 0, 0, 0);
      oaccS[1] = __builtin_amdgcn_mfma_f32_16x16x32_bf16(ones, pb1.v, oaccS[1], 0, 0, 0);
#pragma unroll
      for (int md = 0; md < 2; ++md) {
        bf16x8 av = *(const bf16x8*)(Vc + (16 * md + ln) * 136 + 32 * ks + 8 * g);
        oacc[md][0] = __builtin_amdgcn_mfma_f32_16x16x32_bf16(av, pb0.v, oacc[md][0], 0, 0, 0);
        oacc[md][1] = __builtin_amdgcn_mfma_f32_16x16x32_bf16(av, pb1.v, oacc[md][1], 0, 0, 0);
      }
    }

    __builtin_amdgcn_sched_barrier(0);
    if (tt < 7) {
      const int nxt = cur ^ 1;
      *(uint4*)&Kl[nxt][kwo] = ka0;  *(uint4*)&Kl[nxt][kwo + 8] = ka1;
      *(uint4*)&Vl[nxt][vwo] = va0;  *(uint4*)&Vl[nxt][vwo + 8] = va1;
      asm volatile("s_waitcnt lgkmcnt(0)" ::: "memory");
      __builtin_amdgcn_s_barrier();
      __builtin_amdgcn_sched_barrier(0);
    }
  }

  // epilogue: normalize, LDS transpose, write ot[B][L][256]
  float rl0 = 1.f / oaccS[0][0];
  float rl1 = 1.f / oaccS[1][0];
#pragma unroll
  for (int md = 0; md < 2; ++md) {
    ushort4 p0, p1;
    p0.x = f2bf(oacc[md][0][0] * rl0); p0.y = f2bf(oacc[md][0][1] * rl0);
    p0.z = f2bf(oacc[md][0][2] * rl0); p0.w = f2bf(oacc[md][0][3] * rl0);
    p1.x = f2bf(oacc[md][1][0] * rl1); p1.y = f2bf(oacc[md][1][1] * rl1);
    p1.z = f2bf(oacc[md][1][2] * rl1); p1.w = f2bf(oacc[md][1][3] * rl1);
    *(ushort4*)&otile[w * 32 + ln][16 * md + 4 * g] = p0;
    *(ushort4*)&otile[w * 32 + 16 + ln][16 * md + 4 * g] = p1;
  }
  __syncthreads();
  {
    int row = t >> 1, half = t & 1;
    uint4 v0 = *(const uint4*)&otile[row][half * 16];
    uint4 v1 = *(const uint4*)&otile[row][half * 16 + 8];
    ushort* dstp = ot + ((size_t)(b * L_ + q0b + row)) * 256 + hh * 32 + half * 16;
    *(uint4*)dstp = v0;
    *(uint4*)(dstp + 8) = v1;
  }
}

// ---------------------------------------------------------------------------
extern "C" void kernel_launch(void* const* d_in, const int* in_sizes, int n_in,
                              void* d_out, int out_size, void* d_ws, size_t ws_size,
                              hipStream_t stream) {
  const float* x      = (const float*)d_in[0];
  const float* gamma  = (const float*)d_in[1];
  const float* beta   = (const float*)d_in[2];
  const float* dw     = (const float*)d_in[3];
  const float* qkv_w  = (const float*)d_in[4];
  const float* qkv_b  = (const float*)d_in[5];
  const float* out_w  = (const float*)d_in[6];
  const float* out_b  = (const float*)d_in[7];
  float* out = (float*)d_out;

  char* ws = (char*)d_ws;
  ushort* ht   = (ushort*)(ws);                   // 4 MiB @0  (dead after qkv)
  ushort* qtb  = (ushort*)(ws + (16u << 20));     // 4 MiB @16
  ushort* ktb  = (ushort*)(ws + (20u << 20));     // 4 MiB @20
  ushort* vbb  = (ushort*)(ws + (24u << 20));     // 4 MiB @24
  ushort* otb  = (ushort*)(ws);                   // 4 MiB @0  (reuse ht)
  ushort* wq   = (ushort*)(ws + (28u << 20));     // 384 KiB @28M
  ushort* wo   = (ushort*)(ws + (28u << 20) + (512u << 10));  // 128 KiB

  gnw_kernel<<<512, 256, 0, stream>>>(x, gamma, beta, dw,
                                      (const float4*)qkv_w, (const float4*)out_w,
                                      (uint2*)wq, (uint2*)wo, ht);
  qkv_fused_kernel<<<dim3(8, 8, B_), 256, 0, stream>>>(ht, wq, qkv_b, qtb, ktb, vbb);
  attn_mfma_kernel<<<512, 256, 0, stream>>>(qtb, ktb, vbb, otb);
  pconv_mfma_kernel<32><<<dim3(8, 4, B_), 256, 0, stream>>>(
      otb, wo, out_b, x, out, 256);
}

// Round 7
// 67.259 us; speedup vs baseline: 1.9452x; 1.0829x over previous
//
#include <hip/hip_runtime.h>
#include <hip/hip_bf16.h>

#define B_ 8
#define C_ 256
#define L_ 1024
#define NH_ 8
#define EPS_ 1e-5f

typedef __attribute__((ext_vector_type(8))) short bf16x8;
typedef __attribute__((ext_vector_type(4))) float f32x4;

static __device__ inline ushort f2bf(float f) {
  union { __hip_bfloat16 b; ushort u; } c;
  c.b = __float2bfloat16(f);
  return c.u;
}

// ---------------------------------------------------------------------------
// Kernel A: blocks 0-255: weight fp32->bf16 convert; blocks 256-511:
// GroupNorm + depthwise conv k=3, output TRANSPOSED bf16 ht[B][L][256]
// ---------------------------------------------------------------------------
__global__ __launch_bounds__(256) void gnw_kernel(
    const float* __restrict__ x, const float* __restrict__ gamma,
    const float* __restrict__ beta, const float* __restrict__ dw,
    const float4* __restrict__ qw, const float4* __restrict__ ow,
    uint2* __restrict__ wq, uint2* __restrict__ wo_,
    ushort* __restrict__ ht) {
  __shared__ float hn[8 * L_];
  __shared__ float ws0[4], ws1[4];
  int t = threadIdx.x;
  if (blockIdx.x < 256) {
    int id = blockIdx.x * 256 + t;
    float4 v;
    uint2* dst;
    if (id < 49152) { v = qw[id]; dst = wq + id; }
    else { v = ow[id - 49152]; dst = wo_ + (id - 49152); }
    union { ushort s[4]; uint2 u; } p;
    p.s[0] = f2bf(v.x); p.s[1] = f2bf(v.y); p.s[2] = f2bf(v.z); p.s[3] = f2bf(v.w);
    *dst = p.u;
    return;
  }
  int blk = blockIdx.x - 256;     // b*32 + g
  int b = blk >> 5, g = blk & 31;
  const size_t base = ((size_t)(b * C_ + g * 8)) * L_;

  float s = 0.f, ss = 0.f;
  float vals[32];
#pragma unroll
  for (int i = 0; i < 32; ++i) {
    int e = t + 256 * i;
    float v = x[base + e];
    vals[i] = v;
    s += v; ss += v * v;
  }
#pragma unroll
  for (int off = 32; off >= 1; off >>= 1) {
    s  += __shfl_xor(s, off);
    ss += __shfl_xor(ss, off);
  }
  int wave = t >> 6;
  if ((t & 63) == 0) { ws0[wave] = s; ws1[wave] = ss; }
  __syncthreads();
  s  = ws0[0] + ws0[1] + ws0[2] + ws0[3];
  ss = ws1[0] + ws1[1] + ws1[2] + ws1[3];
  float mean = s * (1.f / 8192.f);
  float var = ss * (1.f / 8192.f) - mean * mean;
  float rstd = rsqrtf(var + EPS_);

#pragma unroll
  for (int i = 0; i < 32; ++i) {
    int e = t + 256 * i;
    int c = g * 8 + (e >> 10);
    float sc = gamma[c] * rstd;
    hn[e] = (vals[i] - mean) * sc + beta[c];
  }
  __syncthreads();
  float r[32];
#pragma unroll
  for (int i = 0; i < 32; ++i) {
    int e = t + 256 * i;
    int l = e & 1023;
    int c = g * 8 + (i >> 2);
    float w0 = dw[c * 3 + 0], w1 = dw[c * 3 + 1], w2 = dw[c * 3 + 2];
    float a = (l > 0) ? hn[e - 1] : 0.f;
    float m = hn[e];
    float z = (l < 1023) ? hn[e + 1] : 0.f;
    r[i] = w0 * a + w1 * m + w2 * z;
  }
#pragma unroll
  for (int li = 0; li < 4; ++li) {
    int l = t + 256 * li;
    union { ushort s8[8]; uint4 u; } pk;
#pragma unroll
    for (int cl = 0; cl < 8; ++cl) pk.s8[cl] = f2bf(r[4 * cl + li]);
    *(uint4*)(ht + ((size_t)(b * L_ + l)) * 256 + g * 8) = pk.u;
  }
}

// ---------------------------------------------------------------------------
// Kernel B: qkv pointwise conv via MFMA, fused repack epilogue.
// Q is PRE-SCALED by 1/sqrt(C)*log2(e) so attention needs no per-elem scale.
// ---------------------------------------------------------------------------
__global__ __launch_bounds__(256) void qkv_fused_kernel(
    const ushort* __restrict__ Xt, const ushort* __restrict__ Wb,
    const float* __restrict__ bias, ushort* __restrict__ qt,
    ushort* __restrict__ kt, ushort* __restrict__ vb) {
  int bx = blockIdx.x, head = blockIdx.y, b = blockIdx.z;
  int bh = b * 8 + head;
  int t = threadIdx.x;
  int w = t >> 6, l = t & 63;
  int g = l >> 4, ln = l & 15;
  int wl = w >> 1, wo = w & 1;
  int lbase = bx * 128 + wl * 64;

  const ushort* xp = Xt + ((size_t)b * L_ + lbase) * 256;
  const ushort* wp = Wb + (size_t)(head * 96 + wo * 48) * 256;

  f32x4 acc[4][3];
#pragma unroll
  for (int ml = 0; ml < 4; ++ml)
#pragma unroll
    for (int nn = 0; nn < 3; ++nn) acc[ml][nn] = (f32x4){0.f, 0.f, 0.f, 0.f};

  for (int c0 = 0; c0 < 256; c0 += 32) {
    bf16x8 af[4], bf[3];
#pragma unroll
    for (int ml = 0; ml < 4; ++ml)
      af[ml] = *(const bf16x8*)(xp + (size_t)(16 * ml + ln) * 256 + c0 + 8 * g);
#pragma unroll
    for (int nn = 0; nn < 3; ++nn)
      bf[nn] = *(const bf16x8*)(wp + (size_t)(16 * nn + ln) * 256 + c0 + 8 * g);
#pragma unroll
    for (int ml = 0; ml < 4; ++ml)
#pragma unroll
      for (int nn = 0; nn < 3; ++nn)
        acc[ml][nn] = __builtin_amdgcn_mfma_f32_16x16x32_bf16(af[ml], bf[nn], acc[ml][nn], 0, 0, 0);
  }

  // bias
#pragma unroll
  for (int nn = 0; nn < 3; ++nn) {
    float bs = bias[head * 96 + wo * 48 + 16 * nn + ln];
#pragma unroll
    for (int ml = 0; ml < 4; ++ml)
#pragma unroll
      for (int r = 0; r < 4; ++r) acc[ml][nn][r] += bs;
  }

  __shared__ ushort tr[5120];
  const float QSC = 0.0625f * 1.44269504f;   // 1/sqrt(256) * log2(e)

  // rounds 0 (q, scaled), 1 (k): transpose to [l][d] (pad 40), write [bh][l][32]
  for (int rk = 0; rk < 2; ++rk) {
    float sc = rk ? 1.f : QSC;
    __syncthreads();
#pragma unroll
    for (int nn = 0; nn < 3; ++nn) {
      int ocl0 = wo * 48 + 16 * nn;
      if (ocl0 >= rk * 32 && ocl0 < rk * 32 + 32) {
        int d = ocl0 - rk * 32 + ln;
#pragma unroll
        for (int ml = 0; ml < 4; ++ml) {
          int lrow = wl * 64 + 16 * ml + 4 * g;
#pragma unroll
          for (int r = 0; r < 4; ++r)
            tr[(lrow + r) * 40 + d] = f2bf(acc[ml][nn][r] * sc);
        }
      }
    }
    __syncthreads();
    {
      int row = t >> 1, half = t & 1;
      uint4 v0 = *(const uint4*)&tr[row * 40 + half * 16];
      uint4 v1 = *(const uint4*)&tr[row * 40 + half * 16 + 8];
      ushort* dst = (rk ? kt : qt) +
                    ((size_t)bh * L_ + bx * 128 + row) * 32 + half * 16;
      *(uint4*)dst = v0;
      *(uint4*)(dst + 8) = v1;
    }
  }

  // round 2 (v): [d][l] (pad 136), PI-permute on global write
  __syncthreads();
  if (wo == 1) {
#pragma unroll
    for (int nn = 1; nn < 3; ++nn) {
      int d = 16 * (nn - 1) + ln;
#pragma unroll
      for (int ml = 0; ml < 4; ++ml) {
        int lc = wl * 64 + 16 * ml + 4 * g;
        union { ushort s[4]; uint2 u; } pk;
#pragma unroll
        for (int r = 0; r < 4; ++r) pk.s[r] = f2bf(acc[ml][nn][r]);
        *(uint2*)&tr[d * 136 + lc] = pk.u;
      }
    }
  }
  __syncthreads();
  {
    int d = t >> 3, s0 = t & 7;
    ushort* vdst = vb + ((size_t)bh * 32 + d) * L_ + bx * 128;
#pragma unroll
    for (int c = 0; c < 2; ++c) {
      int ch = s0 + 8 * c;
      int jj = ch >> 2, gg = ch & 3;
      uint2 lo = *(const uint2*)&tr[d * 136 + 32 * jj + 4 * gg];
      uint2 hi = *(const uint2*)&tr[d * 136 + 32 * jj + 16 + 4 * gg];
      *(uint4*)(vdst + 32 * jj + 8 * gg) = make_uint4(lo.x, lo.y, hi.x, hi.y);
    }
  }
}

// ---------------------------------------------------------------------------
// Kernel D: out pointwise conv via MFMA + residual (fp32 out).
// ---------------------------------------------------------------------------
template <int OCT>
__global__ __launch_bounds__(256) void pconv_mfma_kernel(
    const ushort* __restrict__ Xt, const ushort* __restrict__ Wb,
    const float* __restrict__ bias, const float* __restrict__ resid,
    float* __restrict__ out, int OC) {
  constexpr int NN = OCT / 16;
  int b = blockIdx.z;
  int t = threadIdx.x;
  int w = t >> 6, l = t & 63;
  int g = l >> 4, ln = l & 15;
  int wl = w >> 1, wo = w & 1;
  int lbase = blockIdx.x * 128 + wl * 64;
  int ocbase = blockIdx.y * (2 * OCT) + wo * OCT;

  const ushort* xp = Xt + ((size_t)b * L_ + lbase) * 256;
  const ushort* wp = Wb + (size_t)ocbase * 256;

  f32x4 acc[4][NN];
#pragma unroll
  for (int ml = 0; ml < 4; ++ml)
#pragma unroll
    for (int nn = 0; nn < NN; ++nn) acc[ml][nn] = (f32x4){0.f, 0.f, 0.f, 0.f};

  for (int c0 = 0; c0 < 256; c0 += 32) {
    bf16x8 af[4], bf[NN];
#pragma unroll
    for (int ml = 0; ml < 4; ++ml)
      af[ml] = *(const bf16x8*)(xp + (size_t)(16 * ml + ln) * 256 + c0 + 8 * g);
#pragma unroll
    for (int nn = 0; nn < NN; ++nn)
      bf[nn] = *(const bf16x8*)(wp + (size_t)(16 * nn + ln) * 256 + c0 + 8 * g);
#pragma unroll
    for (int ml = 0; ml < 4; ++ml)
#pragma unroll
      for (int nn = 0; nn < NN; ++nn)
        acc[ml][nn] = __builtin_amdgcn_mfma_f32_16x16x32_bf16(af[ml], bf[nn], acc[ml][nn], 0, 0, 0);
  }

#pragma unroll
  for (int nn = 0; nn < NN; ++nn) {
    int oc = ocbase + 16 * nn + ln;
    float bs = bias[oc];
#pragma unroll
    for (int ml = 0; ml < 4; ++ml) {
      int lr = lbase + 16 * ml + 4 * g;
      size_t ob = ((size_t)b * OC + oc) * L_ + lr;
      float4 rd = *(const float4*)(resid + ob);
      float4 st = make_float4(acc[ml][nn][0] + bs + rd.x, acc[ml][nn][1] + bs + rd.y,
                              acc[ml][nn][2] + bs + rd.z, acc[ml][nn][3] + bs + rd.w);
      *(float4*)(out + ob) = st;
    }
  }
}

// ---------------------------------------------------------------------------
// Kernel C: MFMA flash attention, NO max-subtraction (scores bounded by
// construction; Q pre-scaled). Tile body: QK-MFMA -> exp -> pack -> PV-MFMA.
// dbuf LDS staging, padded conflict-free layouts, XCD swizzle. grid 512.
// ---------------------------------------------------------------------------
__global__ __launch_bounds__(256) void attn_mfma_kernel(
    const ushort* __restrict__ qt, const ushort* __restrict__ kt,
    const ushort* __restrict__ vb, ushort* __restrict__ ot) {
  const int id = blockIdx.x;
  const int bh = ((id & 7) << 3) | (id >> 6);
  const int qtile = (id >> 3) & 7;
  const int b = bh >> 3, hh = bh & 7;
  const int t = threadIdx.x;
  const int w = t >> 6, l = t & 63;
  const int g = l >> 4, ln = l & 15;
  const int q0b = qtile * 128;
  const int q0 = q0b + w * 32;

  __shared__ ushort Kl[2][128 * 40];          // padded rows: 80B stride
  __shared__ ushort Vl[2][32 * 136];          // padded rows: 272B stride
  __shared__ __align__(16) ushort otile[128][40];

  const ushort* qbase = qt + (size_t)bh * (L_ * 32);
  const ushort* kbase = kt + (size_t)bh * (L_ * 32);
  const ushort* vbase = vb + (size_t)bh * (32 * L_);

  // staging geometry
  const int krow = t >> 1, khalf = t & 1;
  const ushort* kg = kbase + krow * 32 + khalf * 16;
  const int kwo = krow * 40 + khalf * 16;
  const int vrow = t >> 3, vc = (t & 7) * 16;
  const ushort* vg = vbase + (size_t)vrow * L_ + vc;
  const int vwo = vrow * 136 + vc;

  const f32x4 z4 = {0.f, 0.f, 0.f, 0.f};
  bf16x8 bq[2];
  bq[0] = *(const bf16x8*)(qbase + (size_t)(q0 + ln) * 32 + g * 8);
  bq[1] = *(const bf16x8*)(qbase + (size_t)(q0 + 16 + ln) * 32 + g * 8);

  union { ushort s[8]; bf16x8 v; } onesu;
#pragma unroll
  for (int i = 0; i < 8; ++i) onesu.s[i] = 0x3F80;  // bf16 1.0
  const bf16x8 ones = onesu.v;

  f32x4 oacc[2][2];  // [md][nq]
  oacc[0][0] = z4; oacc[0][1] = z4; oacc[1][0] = z4; oacc[1][1] = z4;
  f32x4 oaccS[2] = {z4, z4};

  // prologue: stage tile 0
  uint4 ka0, ka1, va0, va1;
  ka0 = *(const uint4*)kg;       ka1 = *(const uint4*)(kg + 8);
  va0 = *(const uint4*)vg;       va1 = *(const uint4*)(vg + 8);
  __builtin_amdgcn_sched_barrier(0);
  *(uint4*)&Kl[0][kwo] = ka0;    *(uint4*)&Kl[0][kwo + 8] = ka1;
  *(uint4*)&Vl[0][vwo] = va0;    *(uint4*)&Vl[0][vwo + 8] = va1;
  asm volatile("s_waitcnt lgkmcnt(0)" ::: "memory");
  __builtin_amdgcn_s_barrier();
  __builtin_amdgcn_sched_barrier(0);

  for (int tt = 0; tt < 8; ++tt) {
    const int cur = tt & 1;
    if (tt < 7) {
      ka0 = *(const uint4*)(kg + (tt + 1) * 4096);
      ka1 = *(const uint4*)(kg + (tt + 1) * 4096 + 8);
      va0 = *(const uint4*)(vg + (tt + 1) * 128);
      va1 = *(const uint4*)(vg + (tt + 1) * 128 + 8);
    }
    __builtin_amdgcn_sched_barrier(0);

    const ushort* Kc = &Kl[cur][0];
    const ushort* Vc = &Vl[cur][0];

    // QK^T  (S already in log2-units thanks to Q pre-scale)
    f32x4 sacc[8][2];
#pragma unroll
    for (int mk = 0; mk < 8; ++mk) {
      bf16x8 ak = *(const bf16x8*)(Kc + (16 * mk + ln) * 40 + g * 8);
      sacc[mk][0] = __builtin_amdgcn_mfma_f32_16x16x32_bf16(ak, bq[0], z4, 0, 0, 0);
      sacc[mk][1] = __builtin_amdgcn_mfma_f32_16x16x32_bf16(ak, bq[1], z4, 0, 0, 0);
    }

    // exp + pack to bf16 (no max subtraction, no cross-lane ops)
    uint upk[2][8][2];
#pragma unroll
    for (int nq = 0; nq < 2; ++nq) {
#pragma unroll
      for (int mk = 0; mk < 8; ++mk) {
        float e0 = exp2f(sacc[mk][nq][0]);
        float e1 = exp2f(sacc[mk][nq][1]);
        float e2 = exp2f(sacc[mk][nq][2]);
        float e3 = exp2f(sacc[mk][nq][3]);
        uint u0, u1;
        asm("v_cvt_pk_bf16_f32 %0, %1, %2" : "=v"(u0) : "v"(e0), "v"(e1));
        asm("v_cvt_pk_bf16_f32 %0, %1, %2" : "=v"(u1) : "v"(e2), "v"(e3));
        upk[nq][mk][0] = u0; upk[nq][mk][1] = u1;
      }
    }

    // PV + denominator
#pragma unroll
    for (int ks = 0; ks < 4; ++ks) {
      union { uint u[4]; bf16x8 v; } pb0, pb1;
      pb0.u[0] = upk[0][2 * ks][0]; pb0.u[1] = upk[0][2 * ks][1];
      pb0.u[2] = upk[0][2 * ks + 1][0]; pb0.u[3] = upk[0][2 * ks + 1][1];
      pb1.u[0] = upk[1][2 * ks][0]; pb1.u[1] = upk[1][2 * ks][1];
      pb1.u[2] = upk[1][2 * ks + 1][0]; pb1.u[3] = upk[1][2 * ks + 1][1];
      oaccS[0] = __builtin_amdgcn_mfma_f32_16x16x32_bf16(ones, pb0.v, oaccS[0], 0, 0, 0);
      oaccS[1] = __builtin_amdgcn_mfma_f32_16x16x32_bf16(ones, pb1.v, oaccS[1], 0, 0, 0);
#pragma unroll
      for (int md = 0; md < 2; ++md) {
        bf16x8 av = *(const bf16x8*)(Vc + (16 * md + ln) * 136 + 32 * ks + 8 * g);
        oacc[md][0] = __builtin_amdgcn_mfma_f32_16x16x32_bf16(av, pb0.v, oacc[md][0], 0, 0, 0);
        oacc[md][1] = __builtin_amdgcn_mfma_f32_16x16x32_bf16(av, pb1.v, oacc[md][1], 0, 0, 0);
      }
    }

    __builtin_amdgcn_sched_barrier(0);
    if (tt < 7) {
      const int nxt = cur ^ 1;
      *(uint4*)&Kl[nxt][kwo] = ka0;  *(uint4*)&Kl[nxt][kwo + 8] = ka1;
      *(uint4*)&Vl[nxt][vwo] = va0;  *(uint4*)&Vl[nxt][vwo + 8] = va1;
      asm volatile("s_waitcnt lgkmcnt(0)" ::: "memory");
      __builtin_amdgcn_s_barrier();
      __builtin_amdgcn_sched_barrier(0);
    }
  }

  // epilogue: normalize, LDS transpose, write ot[B][L][256]
  float rl0 = 1.f / oaccS[0][0];
  float rl1 = 1.f / oaccS[1][0];
#pragma unroll
  for (int md = 0; md < 2; ++md) {
    ushort4 p0, p1;
    p0.x = f2bf(oacc[md][0][0] * rl0); p0.y = f2bf(oacc[md][0][1] * rl0);
    p0.z = f2bf(oacc[md][0][2] * rl0); p0.w = f2bf(oacc[md][0][3] * rl0);
    p1.x = f2bf(oacc[md][1][0] * rl1); p1.y = f2bf(oacc[md][1][1] * rl1);
    p1.z = f2bf(oacc[md][1][2] * rl1); p1.w = f2bf(oacc[md][1][3] * rl1);
    *(ushort4*)&otile[w * 32 + ln][16 * md + 4 * g] = p0;
    *(ushort4*)&otile[w * 32 + 16 + ln][16 * md + 4 * g] = p1;
  }
  __syncthreads();
  {
    int row = t >> 1, half = t & 1;
    uint4 v0 = *(const uint4*)&otile[row][half * 16];
    uint4 v1 = *(const uint4*)&otile[row][half * 16 + 8];
    ushort* dstp = ot + ((size_t)(b * L_ + q0b + row)) * 256 + hh * 32 + half * 16;
    *(uint4*)dstp = v0;
    *(uint4*)(dstp + 8) = v1;
  }
}

// ---------------------------------------------------------------------------
extern "C" void kernel_launch(void* const* d_in, const int* in_sizes, int n_in,
                              void* d_out, int out_size, void* d_ws, size_t ws_size,
                              hipStream_t stream) {
  const float* x      = (const float*)d_in[0];
  const float* gamma  = (const float*)d_in[1];
  const float* beta   = (const float*)d_in[2];
  const float* dw     = (const float*)d_in[3];
  const float* qkv_w  = (const float*)d_in[4];
  const float* qkv_b  = (const float*)d_in[5];
  const float* out_w  = (const float*)d_in[6];
  const float* out_b  = (const float*)d_in[7];
  float* out = (float*)d_out;

  char* ws = (char*)d_ws;
  ushort* ht   = (ushort*)(ws);                   // 4 MiB @0  (dead after qkv)
  ushort* qtb  = (ushort*)(ws + (16u << 20));     // 4 MiB @16
  ushort* ktb  = (ushort*)(ws + (20u << 20));     // 4 MiB @20
  ushort* vbb  = (ushort*)(ws + (24u << 20));     // 4 MiB @24
  ushort* otb  = (ushort*)(ws);                   // 4 MiB @0  (reuse ht)
  ushort* wq   = (ushort*)(ws + (28u << 20));     // 384 KiB @28M
  ushort* wo   = (ushort*)(ws + (28u << 20) + (512u << 10));  // 128 KiB

  gnw_kernel<<<512, 256, 0, stream>>>(x, gamma, beta, dw,
                                      (const float4*)qkv_w, (const float4*)out_w,
                                      (uint2*)wq, (uint2*)wo, ht);
  qkv_fused_kernel<<<dim3(8, 8, B_), 256, 0, stream>>>(ht, wq, qkv_b, qtb, ktb, vbb);
  attn_mfma_kernel<<<512, 256, 0, stream>>>(qtb, ktb, vbb, otb);
  pconv_mfma_kernel<32><<<dim3(8, 4, B_), 256, 0, stream>>>(
      otb, wo, out_b, x, out, 256);
}